// Round 1
// baseline (635.304 us; speedup 1.0000x reference)
//
#include <hip/hip_runtime.h>
#include <hip/hip_bf16.h>

// KGE graph encoder, pruned to the backward cone of the 64 CLS nodes.
// Key facts: only h[graph_offsets] (64 nodes) is read; segment softmax /
// aggregation for node n depends only on edges with dst==n; rel_f has only
// 500 distinct rows (project rel_table once per layer).

#define NN   50000      // N_NODES
#define NE   800000     // N_EDGES
#define NR   500        // N_REL
#define HH   8          // heads
#define DD   16         // per-head dim
#define HIDD 128        // HID == IN
#define BB   64         // batch (CLS nodes)

#define MAXE2 16384     // cap on |{e : dst in S2}|   (expect ~1K)
#define MAXS1 16448     // cap on |S1|                (expect ~1.1K)
#define MAXE1 262144    // cap on |{e : dst in S1}|   (expect ~18K)
#define MAXS0 50000     // node set, can't exceed NN  (expect ~19K)

// counters: [0]=cntS1 [1]=cntS0 [2]=cntE2 [3]=cntE1

__global__ void k_init(int* slot2, int* slot1, int* slot0, int* counters,
                       float* h1acc, float* den1, float* out2, float* den2) {
    int i = blockIdx.x * blockDim.x + threadIdx.x;
    int stride = gridDim.x * blockDim.x;
    for (int n = i; n < NN; n += stride) { slot2[n] = -1; slot1[n] = -1; slot0[n] = -1; }
    for (int n = i; n < MAXS1 * HIDD; n += stride) h1acc[n] = 0.f;
    for (int n = i; n < MAXS1 * HH; n += stride) den1[n] = 0.f;
    for (int n = i; n < BB * HIDD; n += stride) out2[n] = 0.f;
    for (int n = i; n < BB * HH; n += stride) den2[n] = 0.f;
    if (i < 8) counters[i] = 0;
}

__global__ void k_seed(const int* goffs, int* slot2, int* slot1, int* nodesS1,
                       int* counters) {
    int i = threadIdx.x;
    if (i < BB) {
        int n = goffs[i];
        slot2[n] = i;        // graph index
        slot1[n] = -2;       // member of S1, slot assigned in k_finS1
        nodesS1[i] = n;
    }
    if (i == 0) counters[0] = BB;
}

__global__ void k_scan2(const int* src, const int* dst, const int* slot2,
                        int* slot1, int* e2list, int* nodesS1, int* counters) {
    int i = blockIdx.x * blockDim.x + threadIdx.x;
    int stride = gridDim.x * blockDim.x;
    for (int e = i; e < NE; e += stride) {
        int d = dst[e];
        if (slot2[d] >= 0) {
            int k = atomicAdd(&counters[2], 1);
            if (k < MAXE2) e2list[k] = e;
            int s = src[e];
            int old = atomicCAS(&slot1[s], -1, -2);
            if (old == -1) {
                int j = atomicAdd(&counters[0], 1);
                if (j < MAXS1) nodesS1[j] = s;
            }
        }
    }
}

__global__ void k_finS1(int* slot1, const int* nodesS1, int* slot0, int* nodesS0,
                        int* counters) {
    int k = blockIdx.x * blockDim.x + threadIdx.x;
    int cnt = counters[0]; if (cnt > MAXS1) cnt = MAXS1;
    if (k < cnt) {
        int n = nodesS1[k];
        slot1[n] = k;
        slot0[n] = -2;       // S1 subset of S0 (dst features needed for er)
        nodesS0[k] = n;
    }
    if (k == 0) counters[1] = cnt;
}

__global__ void k_scan1(const int* src, const int* dst, const int* slot1,
                        int* slot0, int* e1list, int* nodesS0, int* counters) {
    int i = blockIdx.x * blockDim.x + threadIdx.x;
    int stride = gridDim.x * blockDim.x;
    for (int e = i; e < NE; e += stride) {
        if (slot1[dst[e]] >= 0) {
            int k = atomicAdd(&counters[3], 1);
            if (k < MAXE1) e1list[k] = e;
            int s = src[e];
            int old = atomicCAS(&slot0[s], -1, -2);
            if (old == -1) {
                int j = atomicAdd(&counters[1], 1);
                if (j < MAXS0) nodesS0[j] = s;
            }
        }
    }
}

__global__ void k_finS0(int* slot0, const int* nodesS0, const int* counters) {
    int k = blockIdx.x * blockDim.x + threadIdx.x;
    int cnt = counters[1]; if (cnt > MAXS0) cnt = MAXS0;
    if (k < cnt) slot0[nodesS0[k]] = k;
}

// rproj[l][r][:] = rel_table[r] @ W_rel[l];  ee[l][r][h] = <rproj head h, attn_e[l][h]>
__global__ void k_rel(const float* rel_table, const float* W_rel, const float* attn_e,
                      float* rproj, float* ee) {
    int b = blockIdx.x;               // 0 .. 2*NR-1
    int l = b / NR, r = b % NR;
    int t = threadIdx.x;              // 0..127
    __shared__ float row[HIDD];
    __shared__ float rp[HIDD];
    row[t] = rel_table[r * HIDD + t];
    __syncthreads();
    const float* W = W_rel + l * HIDD * HIDD;
    float acc = 0.f;
    for (int j = 0; j < HIDD; j++) acc += row[j] * W[j * HIDD + t];
    rproj[(l * NR + r) * HIDD + t] = acc;
    rp[t] = acc;
    __syncthreads();
    if (t < HH) {
        float s = 0.f;
        for (int d = 0; d < DD; d++) s += rp[t * DD + d] * attn_e[(l * HH + t) * DD + d];
        ee[(l * NR + r) * HH + t] = s;
    }
}

// feat0 (layer-0 projected features) + el0/er0 for all S0 nodes
__global__ void k_feat0(const int* nodesS0, const int* counters, const int* ent_ids,
                        const float* ent_table, const float* W_ent,
                        const float* attn_l, const float* attn_r,
                        float* feat0, float* el0, float* er0) {
    int t = threadIdx.x;              // 0..127
    int cnt = counters[1]; if (cnt > MAXS0) cnt = MAXS0;
    __shared__ float row[HIDD];
    __shared__ float f[HIDD];
    for (int k = blockIdx.x; k < cnt; k += gridDim.x) {
        int n = nodesS0[k];
        row[t] = ent_table[(long)ent_ids[n] * HIDD + t];
        __syncthreads();
        float acc = 0.f;
        for (int j = 0; j < HIDD; j++) acc += row[j] * W_ent[j * HIDD + t];
        feat0[k * HIDD + t] = acc;
        f[t] = acc;
        __syncthreads();
        if (t < HH) {
            float s = 0.f;
            for (int d = 0; d < DD; d++) s += f[t * DD + d] * attn_l[t * DD + d];
            el0[k * HH + t] = s;
        } else if (t < 2 * HH) {
            int h = t - HH;
            float s = 0.f;
            for (int d = 0; d < DD; d++) s += f[h * DD + d] * attn_r[h * DD + d];
            er0[k * HH + h] = s;
        }
    }
}

// layer-1 edge scores -> ex1, den1
__global__ void k_score1(const int* e1list, const int* counters,
                         const int* src, const int* dst, const int* rel_ids,
                         const int* slot0, const int* slot1,
                         const float* el0, const float* er0, const float* ee0,
                         float* ex1, float* den1) {
    int i = blockIdx.x * blockDim.x + threadIdx.x;
    int stride = gridDim.x * blockDim.x;
    int cnt = counters[3]; if (cnt > MAXE1) cnt = MAXE1;
    int total = cnt * HH;
    for (; i < total; i += stride) {
        int eidx = i >> 3, h = i & 7;
        int e = e1list[eidx];
        int ks  = slot0[src[e]];
        int kd0 = slot0[dst[e]];
        int kd1 = slot1[dst[e]];
        int rid = rel_ids[e];
        float sc = el0[ks * HH + h] + er0[kd0 * HH + h] + ee0[rid * HH + h];
        sc = sc >= 0.f ? sc : 0.2f * sc;
        float ex = expf(sc);
        ex1[eidx * HH + h] = ex;
        atomicAdd(&den1[kd1 * HH + h], ex);
    }
}

// layer-1 messages -> h1acc
__global__ void k_msg1(const int* e1list, const int* counters,
                       const int* src, const int* dst, const int* rel_ids,
                       const int* slot0, const int* slot1,
                       const float* feat0, const float* rproj0, const float* ex1,
                       float* h1acc) {
    int i = blockIdx.x * blockDim.x + threadIdx.x;
    int stride = gridDim.x * blockDim.x;
    int cnt = counters[3]; if (cnt > MAXE1) cnt = MAXE1;
    int total = cnt * HIDD;
    for (; i < total; i += stride) {
        int eidx = i >> 7, col = i & 127;
        int e = e1list[eidx];
        int ks  = slot0[src[e]];
        int kd  = slot1[dst[e]];
        int rid = rel_ids[e];
        float ex = ex1[eidx * HH + (col >> 4)];
        float v = (feat0[ks * HIDD + col] + rproj0[rid * HIDD + col]) * ex;
        atomicAdd(&h1acc[kd * HIDD + col], v);
    }
}

// h1 = h1acc/den1 (0 if no edges), then feat1 = h1 @ W_ent[1], el1/er1
__global__ void k_feat1(const int* counters, const float* h1acc, const float* den1,
                        const float* W_ent1, const float* attn_l1, const float* attn_r1,
                        float* feat1, float* el1, float* er1) {
    int t = threadIdx.x;
    int cnt = counters[0]; if (cnt > MAXS1) cnt = MAXS1;
    __shared__ float row[HIDD];
    __shared__ float f[HIDD];
    for (int k = blockIdx.x; k < cnt; k += gridDim.x) {
        float den = den1[k * HH + (t >> 4)];
        row[t] = den > 0.f ? h1acc[k * HIDD + t] / den : 0.f;
        __syncthreads();
        float acc = 0.f;
        for (int j = 0; j < HIDD; j++) acc += row[j] * W_ent1[j * HIDD + t];
        feat1[k * HIDD + t] = acc;
        f[t] = acc;
        __syncthreads();
        if (t < HH) {
            float s = 0.f;
            for (int d = 0; d < DD; d++) s += f[t * DD + d] * attn_l1[t * DD + d];
            el1[k * HH + t] = s;
        } else if (t < 2 * HH) {
            int h = t - HH;
            float s = 0.f;
            for (int d = 0; d < DD; d++) s += f[h * DD + d] * attn_r1[h * DD + d];
            er1[k * HH + h] = s;
        }
    }
}

// layer-2 edge scores -> ex2, den2
__global__ void k_score2(const int* e2list, const int* counters,
                         const int* src, const int* dst, const int* rel_ids,
                         const int* slot1, const int* slot2,
                         const float* el1, const float* er1, const float* ee1,
                         float* ex2, float* den2) {
    int i = blockIdx.x * blockDim.x + threadIdx.x;
    int stride = gridDim.x * blockDim.x;
    int cnt = counters[2]; if (cnt > MAXE2) cnt = MAXE2;
    int total = cnt * HH;
    for (; i < total; i += stride) {
        int eidx = i >> 3, h = i & 7;
        int e = e2list[eidx];
        int ks  = slot1[src[e]];
        int kd1 = slot1[dst[e]];
        int g   = slot2[dst[e]];
        int rid = rel_ids[e];
        float sc = el1[ks * HH + h] + er1[kd1 * HH + h] + ee1[rid * HH + h];
        sc = sc >= 0.f ? sc : 0.2f * sc;
        float ex = expf(sc);
        ex2[eidx * HH + h] = ex;
        atomicAdd(&den2[g * HH + h], ex);
    }
}

// layer-2 messages -> out2
__global__ void k_msg2(const int* e2list, const int* counters,
                       const int* src, const int* dst, const int* rel_ids,
                       const int* slot1, const int* slot2,
                       const float* feat1, const float* rproj1, const float* ex2,
                       float* out2) {
    int i = blockIdx.x * blockDim.x + threadIdx.x;
    int stride = gridDim.x * blockDim.x;
    int cnt = counters[2]; if (cnt > MAXE2) cnt = MAXE2;
    int total = cnt * HIDD;
    for (; i < total; i += stride) {
        int eidx = i >> 7, col = i & 127;
        int e = e2list[eidx];
        int ks  = slot1[src[e]];
        int g   = slot2[dst[e]];
        int rid = rel_ids[e];
        float ex = ex2[eidx * HH + (col >> 4)];
        float v = (feat1[ks * HIDD + col] + rproj1[rid * HIDD + col]) * ex;
        atomicAdd(&out2[g * HIDD + col], v);
    }
}

__global__ void k_out(const float* out2, const float* den2, float* out) {
    int i = blockIdx.x * blockDim.x + threadIdx.x;
    if (i >= BB * HIDD) return;
    int g = i >> 7, col = i & 127;
    float den = den2[g * HH + (col >> 4)];
    out[i] = den > 0.f ? out2[i] / den : 0.f;
}

extern "C" void kernel_launch(void* const* d_in, const int* in_sizes, int n_in,
                              void* d_out, int out_size, void* d_ws, size_t ws_size,
                              hipStream_t stream) {
    const float* ent_table = (const float*)d_in[0];
    const float* rel_table = (const float*)d_in[1];
    const float* W_ent     = (const float*)d_in[2];   // [2,128,128]
    const float* W_rel     = (const float*)d_in[3];   // [2,128,128]
    const float* attn_l    = (const float*)d_in[4];   // [2,8,16]
    const float* attn_r    = (const float*)d_in[5];
    const float* attn_e    = (const float*)d_in[6];
    const int*   ent_ids   = (const int*)d_in[7];
    const int*   rel_ids   = (const int*)d_in[8];
    const int*   src       = (const int*)d_in[9];
    const int*   dst       = (const int*)d_in[10];
    const int*   goffs     = (const int*)d_in[11];
    float*       out       = (float*)d_out;

    char* p = (char*)d_ws;
    auto alloc = [&](size_t nbytes) {
        void* q = (void*)p;
        p += (nbytes + 255) & ~(size_t)255;
        return q;
    };
    float* rproj   = (float*)alloc((size_t)2 * NR * HIDD * 4);
    float* ee      = (float*)alloc((size_t)2 * NR * HH * 4);
    int*   slot2   = (int*)alloc((size_t)NN * 4);
    int*   slot1   = (int*)alloc((size_t)NN * 4);
    int*   slot0   = (int*)alloc((size_t)NN * 4);
    int*   nodesS1 = (int*)alloc((size_t)MAXS1 * 4);
    int*   nodesS0 = (int*)alloc((size_t)MAXS0 * 4);
    int*   e2list  = (int*)alloc((size_t)MAXE2 * 4);
    int*   e1list  = (int*)alloc((size_t)MAXE1 * 4);
    int*   counters= (int*)alloc(8 * 4);
    float* feat0   = (float*)alloc((size_t)MAXS0 * HIDD * 4);
    float* el0     = (float*)alloc((size_t)MAXS0 * HH * 4);
    float* er0     = (float*)alloc((size_t)MAXS0 * HH * 4);
    float* ex1     = (float*)alloc((size_t)MAXE1 * HH * 4);
    float* h1acc   = (float*)alloc((size_t)MAXS1 * HIDD * 4);
    float* den1    = (float*)alloc((size_t)MAXS1 * HH * 4);
    float* feat1   = (float*)alloc((size_t)MAXS1 * HIDD * 4);
    float* el1     = (float*)alloc((size_t)MAXS1 * HH * 4);
    float* er1     = (float*)alloc((size_t)MAXS1 * HH * 4);
    float* ex2     = (float*)alloc((size_t)MAXE2 * HH * 4);
    float* out2    = (float*)alloc((size_t)BB * HIDD * 4);
    float* den2    = (float*)alloc((size_t)BB * HH * 4);

    const float* rproj0 = rproj;
    const float* rproj1 = rproj + (size_t)NR * HIDD;
    const float* ee0 = ee;
    const float* ee1 = ee + (size_t)NR * HH;
    const float* W_ent0 = W_ent;
    const float* W_ent1 = W_ent + HIDD * HIDD;
    const float* attn_l0 = attn_l, *attn_l1 = attn_l + HH * DD;
    const float* attn_r0 = attn_r, *attn_r1 = attn_r + HH * DD;

    hipLaunchKernelGGL(k_init, dim3(512), dim3(256), 0, stream,
                       slot2, slot1, slot0, counters, h1acc, den1, out2, den2);
    hipLaunchKernelGGL(k_seed, dim3(1), dim3(64), 0, stream,
                       goffs, slot2, slot1, nodesS1, counters);
    hipLaunchKernelGGL(k_scan2, dim3(1024), dim3(256), 0, stream,
                       src, dst, slot2, slot1, e2list, nodesS1, counters);
    hipLaunchKernelGGL(k_finS1, dim3((MAXS1 + 255) / 256), dim3(256), 0, stream,
                       slot1, nodesS1, slot0, nodesS0, counters);
    hipLaunchKernelGGL(k_scan1, dim3(1024), dim3(256), 0, stream,
                       src, dst, slot1, slot0, e1list, nodesS0, counters);
    hipLaunchKernelGGL(k_finS0, dim3((MAXS0 + 255) / 256), dim3(256), 0, stream,
                       slot0, nodesS0, counters);
    hipLaunchKernelGGL(k_rel, dim3(2 * NR), dim3(HIDD), 0, stream,
                       rel_table, W_rel, attn_e, rproj, ee);
    hipLaunchKernelGGL(k_feat0, dim3(2048), dim3(HIDD), 0, stream,
                       nodesS0, counters, ent_ids, ent_table, W_ent0,
                       attn_l0, attn_r0, feat0, el0, er0);
    hipLaunchKernelGGL(k_score1, dim3(512), dim3(256), 0, stream,
                       e1list, counters, src, dst, rel_ids, slot0, slot1,
                       el0, er0, ee0, ex1, den1);
    hipLaunchKernelGGL(k_msg1, dim3(2048), dim3(256), 0, stream,
                       e1list, counters, src, dst, rel_ids, slot0, slot1,
                       feat0, rproj0, ex1, h1acc);
    hipLaunchKernelGGL(k_feat1, dim3(512), dim3(HIDD), 0, stream,
                       counters, h1acc, den1, W_ent1, attn_l1, attn_r1,
                       feat1, el1, er1);
    hipLaunchKernelGGL(k_score2, dim3(256), dim3(256), 0, stream,
                       e2list, counters, src, dst, rel_ids, slot1, slot2,
                       el1, er1, ee1, ex2, den2);
    hipLaunchKernelGGL(k_msg2, dim3(256), dim3(256), 0, stream,
                       e2list, counters, src, dst, rel_ids, slot1, slot2,
                       feat1, rproj1, ex2, out2);
    hipLaunchKernelGGL(k_out, dim3((BB * HIDD + 255) / 256), dim3(256), 0, stream,
                       out2, den2, out);
}

// Round 2
// 426.034 us; speedup vs baseline: 1.4912x; 1.4912x over previous
//
#include <hip/hip_runtime.h>
#include <hip/hip_bf16.h>

// KGE graph encoder, pruned to the backward cone of the 64 CLS nodes.
// R2: block-aggregated frontier scans (LDS buffer + one global atomic per
// flush) replacing per-hit same-address device atomics (206us -> ~25us each);
// S1-sized zeroing; 8-node-tiled feat0 to amortize W_ent reads.

#define NN   50000      // N_NODES
#define NE   800000     // N_EDGES
#define NR   500        // N_REL
#define HH   8          // heads
#define DD   16         // per-head dim
#define HIDD 128        // HID == IN
#define BB   64         // batch (CLS nodes)

#define MAXE2 16384     // cap on |{e : dst in S2}|   (expect ~1K)
#define MAXS1 16448     // cap on |S1|                (expect ~1.1K)
#define MAXE1 262144    // cap on |{e : dst in S1}|   (expect ~18K)
#define MAXS0 50000     // node set, can't exceed NN  (expect ~19K)

// counters: [0]=cntS1 [1]=cntS0 [2]=cntE2 [3]=cntE1

__global__ void k_init(int* slot2, int* slot1, int* slot0, int* counters,
                       float* out2, float* den2) {
    int i = blockIdx.x * blockDim.x + threadIdx.x;
    int stride = gridDim.x * blockDim.x;
    for (int n = i; n < NN; n += stride) { slot2[n] = -1; slot1[n] = -1; slot0[n] = -1; }
    for (int n = i; n < BB * HIDD; n += stride) out2[n] = 0.f;
    for (int n = i; n < BB * HH; n += stride) den2[n] = 0.f;
    if (i < 8) counters[i] = 0;
}

__global__ void k_seed(const int* goffs, int* slot2, int* slot1, int* nodesS1,
                       int* counters) {
    int i = threadIdx.x;
    if (i < BB) {
        int n = goffs[i];
        slot2[n] = i;        // graph index
        slot1[n] = -2;       // member of S1, slot assigned in k_finS1
        nodesS1[i] = n;
    }
    if (i == 0) counters[0] = BB;
}

// Generic frontier scan: edges whose dst is in slotHit (>=0) are appended to
// elist; their src nodes are CAS-claimed in slotNew and appended to nodes.
// All list appends are block-aggregated in LDS; one global atomicAdd per
// flush (instead of one per hit -> kills cross-XCD same-line serialization).
#define EBUF 1024
#define NBUF 512
__global__ void k_scan(const int* __restrict__ src, const int* __restrict__ dst,
                       const int* __restrict__ slotHit, int* __restrict__ slotNew,
                       int* elist, int elistCap, int* nodes, int nodesCap,
                       int* counters, int cntE, int cntN) {
    __shared__ int lE[EBUF];
    __shared__ int lN[NBUF];
    __shared__ int cEsh, cNsh, baseE, baseN;
    if (threadIdx.x == 0) { cEsh = 0; cNsh = 0; }
    __syncthreads();
    int per = (NE + gridDim.x - 1) / gridDim.x;
    int lo = blockIdx.x * per;
    int hi = lo + per; if (hi > NE) hi = NE;
    for (int base = lo; base < hi; base += blockDim.x) {
        int e = base + threadIdx.x;
        if (e < hi) {
            int d = dst[e];
            if (slotHit[d] >= 0) {
                int pos = atomicAdd(&cEsh, 1);   // LDS atomic: cheap
                lE[pos] = e;                     // bounded: flush threshold guarantees pos < EBUF
                int s = src[e];
                int old = atomicCAS(&slotNew[s], -1, -2);  // scattered, fine
                if (old == -1) {
                    int p2 = atomicAdd(&cNsh, 1);
                    lN[p2] = s;
                }
            }
        }
        __syncthreads();
        if (cEsh >= EBUF - 256 || cNsh >= NBUF - 256) {
            int nE = cEsh, nN = cNsh;
            if (threadIdx.x == 0) {
                baseE = atomicAdd(&counters[cntE], nE);
                baseN = atomicAdd(&counters[cntN], nN);
            }
            __syncthreads();
            for (int i = threadIdx.x; i < nE; i += blockDim.x) {
                int g = baseE + i; if (g < elistCap) elist[g] = lE[i];
            }
            for (int i = threadIdx.x; i < nN; i += blockDim.x) {
                int g = baseN + i; if (g < nodesCap) nodes[g] = lN[i];
            }
            __syncthreads();
            if (threadIdx.x == 0) { cEsh = 0; cNsh = 0; }
        }
        __syncthreads();
    }
    int nE = cEsh, nN = cNsh;
    if (threadIdx.x == 0) {
        baseE = atomicAdd(&counters[cntE], nE);
        baseN = atomicAdd(&counters[cntN], nN);
    }
    __syncthreads();
    for (int i = threadIdx.x; i < nE; i += blockDim.x) {
        int g = baseE + i; if (g < elistCap) elist[g] = lE[i];
    }
    for (int i = threadIdx.x; i < nN; i += blockDim.x) {
        int g = baseN + i; if (g < nodesCap) nodes[g] = lN[i];
    }
}

__global__ void k_finS1(int* slot1, const int* nodesS1, int* slot0, int* nodesS0,
                        int* counters) {
    int k = blockIdx.x * blockDim.x + threadIdx.x;
    int cnt = counters[0]; if (cnt > MAXS1) cnt = MAXS1;
    if (k < cnt) {
        int n = nodesS1[k];
        slot1[n] = k;
        slot0[n] = -2;       // S1 subset of S0 (dst features needed for er)
        nodesS0[k] = n;
    }
    if (k == 0) counters[1] = cnt;
}

__global__ void k_zeroS1(const int* counters, float* h1acc, float* den1) {
    int cnt = counters[0]; if (cnt > MAXS1) cnt = MAXS1;
    int i = blockIdx.x * blockDim.x + threadIdx.x;
    int stride = gridDim.x * blockDim.x;
    for (int n = i; n < cnt * HIDD; n += stride) h1acc[n] = 0.f;
    for (int n = i; n < cnt * HH; n += stride) den1[n] = 0.f;
}

__global__ void k_finS0(int* slot0, const int* nodesS0, const int* counters) {
    int k = blockIdx.x * blockDim.x + threadIdx.x;
    int cnt = counters[1]; if (cnt > MAXS0) cnt = MAXS0;
    if (k < cnt) slot0[nodesS0[k]] = k;
}

// rproj[l][r][:] = rel_table[r] @ W_rel[l];  ee[l][r][h] = <rproj head h, attn_e[l][h]>
__global__ void k_rel(const float* rel_table, const float* __restrict__ W_rel,
                      const float* attn_e, float* rproj, float* ee) {
    int b = blockIdx.x;               // 0 .. 2*NR-1
    int l = b / NR, r = b % NR;
    int t = threadIdx.x;              // 0..127
    __shared__ float row[HIDD];
    __shared__ float rp[HIDD];
    row[t] = rel_table[r * HIDD + t];
    __syncthreads();
    const float* W = W_rel + l * HIDD * HIDD;
    float acc = 0.f;
    for (int j = 0; j < HIDD; j++) acc += row[j] * W[j * HIDD + t];
    rproj[(l * NR + r) * HIDD + t] = acc;
    rp[t] = acc;
    __syncthreads();
    if (t < HH) {
        float s = 0.f;
        for (int d = 0; d < DD; d++) s += rp[t * DD + d] * attn_e[(l * HH + t) * DD + d];
        ee[(l * NR + r) * HH + t] = s;
    }
}

// feat0 + el0/er0 for all S0 nodes; 8 nodes per block tile so each pass over
// W_ent (64 KB) is amortized across 8 matvecs.
#define FT 8
__global__ void k_feat0(const int* nodesS0, const int* counters, const int* ent_ids,
                        const float* __restrict__ ent_table, const float* __restrict__ W_ent,
                        const float* __restrict__ attn_l, const float* __restrict__ attn_r,
                        float* feat0, float* el0, float* er0) {
    int t = threadIdx.x;              // 0..127
    int cnt = counters[1]; if (cnt > MAXS0) cnt = MAXS0;
    __shared__ float rows[FT][HIDD];
    int nTiles = (cnt + FT - 1) / FT;
    for (int tile = blockIdx.x; tile < nTiles; tile += gridDim.x) {
        int k0 = tile * FT;
        #pragma unroll
        for (int m = 0; m < FT; m++) {
            int k = k0 + m;
            int n = nodesS0[k < cnt ? k : 0];
            rows[m][t] = ent_table[(long)ent_ids[n] * HIDD + t];
        }
        __syncthreads();
        float acc[FT];
        #pragma unroll
        for (int m = 0; m < FT; m++) acc[m] = 0.f;
        for (int j = 0; j < HIDD; j++) {
            float w = W_ent[j * HIDD + t];
            #pragma unroll
            for (int m = 0; m < FT; m++) acc[m] += rows[m][j] * w;  // LDS broadcast
        }
        __syncthreads();
        #pragma unroll
        for (int m = 0; m < FT; m++) {
            int k = k0 + m;
            if (k < cnt) feat0[k * HIDD + t] = acc[m];
            rows[m][t] = acc[m];
        }
        __syncthreads();
        // 8 nodes x 8 heads x {el,er} = 128 tasks, one per thread
        {
            int m = t >> 4, idx = t & 15, h = idx >> 1, isR = idx & 1;
            int k = k0 + m;
            if (k < cnt) {
                const float* av = (isR ? attn_r : attn_l) + h * DD;
                float s = 0.f;
                for (int d = 0; d < DD; d++) s += rows[m][h * DD + d] * av[d];
                if (isR) er0[k * HH + h] = s; else el0[k * HH + h] = s;
            }
        }
        __syncthreads();
    }
}

// layer-1 edge scores -> ex1, den1
__global__ void k_score1(const int* e1list, const int* counters,
                         const int* src, const int* dst, const int* rel_ids,
                         const int* slot0, const int* slot1,
                         const float* el0, const float* er0, const float* ee0,
                         float* ex1, float* den1) {
    int i = blockIdx.x * blockDim.x + threadIdx.x;
    int stride = gridDim.x * blockDim.x;
    int cnt = counters[3]; if (cnt > MAXE1) cnt = MAXE1;
    int total = cnt * HH;
    for (; i < total; i += stride) {
        int eidx = i >> 3, h = i & 7;
        int e = e1list[eidx];
        int ks  = slot0[src[e]];
        int kd0 = slot0[dst[e]];
        int kd1 = slot1[dst[e]];
        int rid = rel_ids[e];
        float sc = el0[ks * HH + h] + er0[kd0 * HH + h] + ee0[rid * HH + h];
        sc = sc >= 0.f ? sc : 0.2f * sc;
        float ex = expf(sc);
        ex1[eidx * HH + h] = ex;
        atomicAdd(&den1[kd1 * HH + h], ex);
    }
}

// layer-1 messages -> h1acc
__global__ void k_msg1(const int* e1list, const int* counters,
                       const int* src, const int* dst, const int* rel_ids,
                       const int* slot0, const int* slot1,
                       const float* __restrict__ feat0, const float* __restrict__ rproj0,
                       const float* __restrict__ ex1, float* h1acc) {
    int i = blockIdx.x * blockDim.x + threadIdx.x;
    int stride = gridDim.x * blockDim.x;
    int cnt = counters[3]; if (cnt > MAXE1) cnt = MAXE1;
    int total = cnt * HIDD;
    for (; i < total; i += stride) {
        int eidx = i >> 7, col = i & 127;
        int e = e1list[eidx];
        int ks  = slot0[src[e]];
        int kd  = slot1[dst[e]];
        int rid = rel_ids[e];
        float ex = ex1[eidx * HH + (col >> 4)];
        float v = (feat0[ks * HIDD + col] + rproj0[rid * HIDD + col]) * ex;
        atomicAdd(&h1acc[kd * HIDD + col], v);
    }
}

// h1 = h1acc/den1 (0 if no edges), then feat1 = h1 @ W_ent[1], el1/er1
__global__ void k_feat1(const int* counters, const float* h1acc, const float* den1,
                        const float* __restrict__ W_ent1,
                        const float* attn_l1, const float* attn_r1,
                        float* feat1, float* el1, float* er1) {
    int t = threadIdx.x;
    int cnt = counters[0]; if (cnt > MAXS1) cnt = MAXS1;
    __shared__ float row[HIDD];
    __shared__ float f[HIDD];
    for (int k = blockIdx.x; k < cnt; k += gridDim.x) {
        float den = den1[k * HH + (t >> 4)];
        row[t] = den > 0.f ? h1acc[k * HIDD + t] / den : 0.f;
        __syncthreads();
        float acc = 0.f;
        for (int j = 0; j < HIDD; j++) acc += row[j] * W_ent1[j * HIDD + t];
        feat1[k * HIDD + t] = acc;
        f[t] = acc;
        __syncthreads();
        if (t < HH) {
            float s = 0.f;
            for (int d = 0; d < DD; d++) s += f[t * DD + d] * attn_l1[t * DD + d];
            el1[k * HH + t] = s;
        } else if (t < 2 * HH) {
            int h = t - HH;
            float s = 0.f;
            for (int d = 0; d < DD; d++) s += f[h * DD + d] * attn_r1[h * DD + d];
            er1[k * HH + h] = s;
        }
        __syncthreads();
    }
}

// layer-2 edge scores -> ex2, den2
__global__ void k_score2(const int* e2list, const int* counters,
                         const int* src, const int* dst, const int* rel_ids,
                         const int* slot1, const int* slot2,
                         const float* el1, const float* er1, const float* ee1,
                         float* ex2, float* den2) {
    int i = blockIdx.x * blockDim.x + threadIdx.x;
    int stride = gridDim.x * blockDim.x;
    int cnt = counters[2]; if (cnt > MAXE2) cnt = MAXE2;
    int total = cnt * HH;
    for (; i < total; i += stride) {
        int eidx = i >> 3, h = i & 7;
        int e = e2list[eidx];
        int ks  = slot1[src[e]];
        int kd1 = slot1[dst[e]];
        int g   = slot2[dst[e]];
        int rid = rel_ids[e];
        float sc = el1[ks * HH + h] + er1[kd1 * HH + h] + ee1[rid * HH + h];
        sc = sc >= 0.f ? sc : 0.2f * sc;
        float ex = expf(sc);
        ex2[eidx * HH + h] = ex;
        atomicAdd(&den2[g * HH + h], ex);
    }
}

// layer-2 messages -> out2
__global__ void k_msg2(const int* e2list, const int* counters,
                       const int* src, const int* dst, const int* rel_ids,
                       const int* slot1, const int* slot2,
                       const float* feat1, const float* rproj1, const float* ex2,
                       float* out2) {
    int i = blockIdx.x * blockDim.x + threadIdx.x;
    int stride = gridDim.x * blockDim.x;
    int cnt = counters[2]; if (cnt > MAXE2) cnt = MAXE2;
    int total = cnt * HIDD;
    for (; i < total; i += stride) {
        int eidx = i >> 7, col = i & 127;
        int e = e2list[eidx];
        int ks  = slot1[src[e]];
        int g   = slot2[dst[e]];
        int rid = rel_ids[e];
        float ex = ex2[eidx * HH + (col >> 4)];
        float v = (feat1[ks * HIDD + col] + rproj1[rid * HIDD + col]) * ex;
        atomicAdd(&out2[g * HIDD + col], v);
    }
}

__global__ void k_out(const float* out2, const float* den2, float* out) {
    int i = blockIdx.x * blockDim.x + threadIdx.x;
    if (i >= BB * HIDD) return;
    int g = i >> 7, col = i & 127;
    float den = den2[g * HH + (col >> 4)];
    out[i] = den > 0.f ? out2[i] / den : 0.f;
}

extern "C" void kernel_launch(void* const* d_in, const int* in_sizes, int n_in,
                              void* d_out, int out_size, void* d_ws, size_t ws_size,
                              hipStream_t stream) {
    const float* ent_table = (const float*)d_in[0];
    const float* rel_table = (const float*)d_in[1];
    const float* W_ent     = (const float*)d_in[2];   // [2,128,128]
    const float* W_rel     = (const float*)d_in[3];   // [2,128,128]
    const float* attn_l    = (const float*)d_in[4];   // [2,8,16]
    const float* attn_r    = (const float*)d_in[5];
    const float* attn_e    = (const float*)d_in[6];
    const int*   ent_ids   = (const int*)d_in[7];
    const int*   rel_ids   = (const int*)d_in[8];
    const int*   src       = (const int*)d_in[9];
    const int*   dst       = (const int*)d_in[10];
    const int*   goffs     = (const int*)d_in[11];
    float*       out       = (float*)d_out;

    char* p = (char*)d_ws;
    auto alloc = [&](size_t nbytes) {
        void* q = (void*)p;
        p += (nbytes + 255) & ~(size_t)255;
        return q;
    };
    float* rproj   = (float*)alloc((size_t)2 * NR * HIDD * 4);
    float* ee      = (float*)alloc((size_t)2 * NR * HH * 4);
    int*   slot2   = (int*)alloc((size_t)NN * 4);
    int*   slot1   = (int*)alloc((size_t)NN * 4);
    int*   slot0   = (int*)alloc((size_t)NN * 4);
    int*   nodesS1 = (int*)alloc((size_t)MAXS1 * 4);
    int*   nodesS0 = (int*)alloc((size_t)MAXS0 * 4);
    int*   e2list  = (int*)alloc((size_t)MAXE2 * 4);
    int*   e1list  = (int*)alloc((size_t)MAXE1 * 4);
    int*   counters= (int*)alloc(8 * 4);
    float* feat0   = (float*)alloc((size_t)MAXS0 * HIDD * 4);
    float* el0     = (float*)alloc((size_t)MAXS0 * HH * 4);
    float* er0     = (float*)alloc((size_t)MAXS0 * HH * 4);
    float* ex1     = (float*)alloc((size_t)MAXE1 * HH * 4);
    float* h1acc   = (float*)alloc((size_t)MAXS1 * HIDD * 4);
    float* den1    = (float*)alloc((size_t)MAXS1 * HH * 4);
    float* feat1   = (float*)alloc((size_t)MAXS1 * HIDD * 4);
    float* el1     = (float*)alloc((size_t)MAXS1 * HH * 4);
    float* er1     = (float*)alloc((size_t)MAXS1 * HH * 4);
    float* ex2     = (float*)alloc((size_t)MAXE2 * HH * 4);
    float* out2    = (float*)alloc((size_t)BB * HIDD * 4);
    float* den2    = (float*)alloc((size_t)BB * HH * 4);

    const float* rproj0 = rproj;
    const float* rproj1 = rproj + (size_t)NR * HIDD;
    const float* ee0 = ee;
    const float* ee1 = ee + (size_t)NR * HH;
    const float* W_ent0 = W_ent;
    const float* W_ent1 = W_ent + HIDD * HIDD;
    const float* attn_l0 = attn_l, *attn_l1 = attn_l + HH * DD;
    const float* attn_r0 = attn_r, *attn_r1 = attn_r + HH * DD;

    hipLaunchKernelGGL(k_init, dim3(256), dim3(256), 0, stream,
                       slot2, slot1, slot0, counters, out2, den2);
    hipLaunchKernelGGL(k_seed, dim3(1), dim3(64), 0, stream,
                       goffs, slot2, slot1, nodesS1, counters);
    // scan2: edges into S2 (CLS dsts); discovers S1 via slot1
    hipLaunchKernelGGL(k_scan, dim3(512), dim3(256), 0, stream,
                       src, dst, slot2, slot1, e2list, MAXE2, nodesS1, MAXS1,
                       counters, 2, 0);
    hipLaunchKernelGGL(k_finS1, dim3((MAXS1 + 255) / 256), dim3(256), 0, stream,
                       slot1, nodesS1, slot0, nodesS0, counters);
    hipLaunchKernelGGL(k_zeroS1, dim3(256), dim3(256), 0, stream,
                       counters, h1acc, den1);
    // scan1: edges into S1; discovers S0 via slot0
    hipLaunchKernelGGL(k_scan, dim3(512), dim3(256), 0, stream,
                       src, dst, slot1, slot0, e1list, MAXE1, nodesS0, MAXS0,
                       counters, 3, 1);
    hipLaunchKernelGGL(k_finS0, dim3((MAXS0 + 255) / 256), dim3(256), 0, stream,
                       slot0, nodesS0, counters);
    hipLaunchKernelGGL(k_rel, dim3(2 * NR), dim3(HIDD), 0, stream,
                       rel_table, W_rel, attn_e, rproj, ee);
    hipLaunchKernelGGL(k_feat0, dim3(1024), dim3(HIDD), 0, stream,
                       nodesS0, counters, ent_ids, ent_table, W_ent0,
                       attn_l0, attn_r0, feat0, el0, er0);
    hipLaunchKernelGGL(k_score1, dim3(512), dim3(256), 0, stream,
                       e1list, counters, src, dst, rel_ids, slot0, slot1,
                       el0, er0, ee0, ex1, den1);
    hipLaunchKernelGGL(k_msg1, dim3(2048), dim3(256), 0, stream,
                       e1list, counters, src, dst, rel_ids, slot0, slot1,
                       feat0, rproj0, ex1, h1acc);
    hipLaunchKernelGGL(k_feat1, dim3(512), dim3(HIDD), 0, stream,
                       counters, h1acc, den1, W_ent1, attn_l1, attn_r1,
                       feat1, el1, er1);
    hipLaunchKernelGGL(k_score2, dim3(256), dim3(256), 0, stream,
                       e2list, counters, src, dst, rel_ids, slot1, slot2,
                       el1, er1, ee1, ex2, den2);
    hipLaunchKernelGGL(k_msg2, dim3(256), dim3(256), 0, stream,
                       e2list, counters, src, dst, rel_ids, slot1, slot2,
                       feat1, rproj1, ex2, out2);
    hipLaunchKernelGGL(k_out, dim3((BB * HIDD + 255) / 256), dim3(256), 0, stream,
                       out2, den2, out);
}